// Round 2
// baseline (273.448 us; speedup 1.0000x reference)
//
#include <hip/hip_runtime.h>

#define CI 64
#define CO 128
#define HH 64
#define WW 64
#define OH 62
#define OW 62
#define XTW 66   // xT padded row width: 64 real cols + 2 zero cols

typedef __attribute__((ext_vector_type(8))) short short8x;
typedef __attribute__((ext_vector_type(16))) float f32x16;

// Weight scratch + pre-transposed input in module device-globals (not d_ws);
// both fully rewritten every launch (idempotent, graph-capture safe).
__device__ __attribute__((aligned(16))) ushort g_wt[9 * CO * CI];          // [tap][co][ci] bf16
__device__ __attribute__((aligned(16))) ushort g_xt[64 * 64 * XTW * 64];   // [b][h][w(66)][ci] bf16

__device__ __forceinline__ ushort bf16rne(float f) {
    unsigned u = __builtin_bit_cast(unsigned, f);
    u += 0x7fffu + ((u >> 16) & 1u);
    return (ushort)(u >> 16);
}

__device__ __forceinline__ void gld_lds16(const ushort* g, ushort* l) {
    __builtin_amdgcn_global_load_lds(
        (const __attribute__((address_space(1))) unsigned*)g,
        (__attribute__((address_space(3))) unsigned*)l, 16, 0, 0);
}

__global__ __launch_bounds__(256)
void wprep(const float* __restrict__ w) {
    const int idx = blockIdx.x * 256 + threadIdx.x;   // 73728 total
    const int kk = idx >> 13;
    const int rem = idx & 8191;
    const int co = rem >> 6, ci = rem & 63;
    g_wt[idx] = bf16rne(w[(co * 64 + ci) * 9 + kk]);
}

// NCHW f32 -> [b][h][w+pad][ci] bf16 via LDS tile transpose.
// One block per (b,h): reads 64ci x 64w f32 coalesced (float4), writes one
// 66px x 64ci bf16 row fully coalesced (uint4), cols 64/65 zero-filled.
__global__ __launch_bounds__(256)
void xprep(const float* __restrict__ x) {
    __shared__ ushort T[64 * 68];                     // [ci][w + pad4], 8.7 KB
    const int t = threadIdx.x;
    const int h = blockIdx.x, b = blockIdx.y;
    const float* xb = x + ((size_t)b * 64 * 64 + h) * 64;   // + ci*4096 + w

    #pragma unroll
    for (int g = 0; g < 4; ++g) {
        const int ci = g * 16 + (t >> 4);
        const int w0 = (t & 15) * 4;
        const float4 v = *(const float4*)(xb + (size_t)ci * 4096 + w0);
        ushort tmp[4];
        tmp[0] = bf16rne(v.x); tmp[1] = bf16rne(v.y);
        tmp[2] = bf16rne(v.z); tmp[3] = bf16rne(v.w);
        *reinterpret_cast<uint2*>(&T[ci * 68 + w0]) = *reinterpret_cast<const uint2*>(tmp);
    }
    __syncthreads();

    ushort* dst = g_xt + (size_t)(b * 64 + h) * XTW * 64;
    #pragma unroll
    for (int g = 0; g < 2; ++g) {
        const int w = g * 32 + (t >> 3);
        const int cg = t & 7;
        ushort tmp[8];
        #pragma unroll
        for (int j = 0; j < 8; ++j) tmp[j] = T[(cg * 8 + j) * 68 + w];
        *reinterpret_cast<uint4*>(dst + w * 64 + cg * 8) = *reinterpret_cast<const uint4*>(tmp);
    }
    if (t < 16) {   // zero the 2 pad columns (px 64,65): 256 B
        const uint4 z{0, 0, 0, 0};
        *reinterpret_cast<uint4*>(dst + 64 * 64 + t * 8) = z;
    }
}

// Round-3 topology (grid 31x64, 2 output rows/block, one terminal epilogue)
// with staging replaced by global_load_lds_dwordx4 from pre-transposed bf16:
//  - 8 (9 for wave 0) gload_lds per wave instead of ~64 strided scalar loads
//    + cvt per thread -> no vv[64] register chain, no serialized HBM trips
//  - XOR swizzle applied on the GLOBAL SOURCE address (rule: gload_lds dest is
//    linear); produces byte-identical LDS content to the proven layout, so the
//    K-loop read pattern (c ^ (px&7)) and epilogue are unchanged.
__global__ __launch_bounds__(256, 3)
void conv_fused(const float* __restrict__ bias, float* __restrict__ out) {
    __shared__ ushort Xl[264 * 64];   // 4 input rows x 66 px, 64 ci (33.8 KB)
    __shared__ float  sB[CO];

    const int tid = threadIdx.x;
    const int wv = tid >> 6, L = tid & 63, l31 = L & 31, q = L >> 5;
    const int h = wv >> 1;           // co half: co base = h*64
    const int rw = wv & 1;           // output row (0/1)
    const int b = blockIdx.y, oh0 = blockIdx.x * 2;

    if (tid < CO) sB[tid] = bias[tid];

    // ---- tap-0 A-fragment loads (verified layout: lane m=l31, k=q*8+j) ----
    const ushort* wbase = g_wt + (h * 64 + l31) * 64 + q * 8;
    short8x wbuf[2][8];   // [dbuf][m*4+s]
    #pragma unroll
    for (int m = 0; m < 2; ++m)
        #pragma unroll
        for (int s = 0; s < 4; ++s)
            wbuf[0][m * 4 + s] = *(const short8x*)(wbase + m * 2048 + s * 16);

    // ---- stage X: 33 KB = 2112 16B-chunks via global_load_lds, src-swizzled ----
    // LDS chunk (px*8 + c) holds ci-group (c ^ (px&7)) of pixel px.
    const ushort* xTb = g_xt + (size_t)((b * 64 + oh0) * XTW) * 64;
    #pragma unroll
    for (int j = 0; j < 8; ++j) {
        const int i = j * 256 + tid;             // chunk index, lane-contiguous
        const int px = i >> 3, c = i & 7;
        gld_lds16(xTb + px * 64 + ((c ^ (px & 7)) * 8),
                  &Xl[(j * 256 + (tid & 192)) * 8]);
    }
    if (tid < 64) {                              // tail chunks 2048..2111 (wave 0)
        const int i = 2048 + tid;
        const int px = i >> 3, c = i & 7;
        gld_lds16(xTb + px * 64 + ((c ^ (px & 7)) * 8), &Xl[2048 * 8]);
    }

    f32x16 acc[2][2];
    #pragma unroll
    for (int i = 0; i < 2; ++i)
        #pragma unroll
        for (int j = 0; j < 2; ++j)
            #pragma unroll
            for (int r = 0; r < 16; ++r) acc[i][j][r] = 0.f;

    __syncthreads();   // the only barrier (drains vmcnt incl. gload_lds)

    // ---- K-loop: 9 taps, A double-buffered in regs, B from swizzled LDS ----
    #pragma unroll
    for (int kk = 0; kk < 9; ++kk) {
        const short8x* wf = wbuf[kk & 1];
        if (kk < 8) {   // prefetch next tap while this tap computes
            const ushort* nb = wbase + (kk + 1) * (CO * CI);
            #pragma unroll
            for (int m = 0; m < 2; ++m)
                #pragma unroll
                for (int s = 0; s < 4; ++s)
                    wbuf[(kk + 1) & 1][m * 4 + s] = *(const short8x*)(nb + m * 2048 + s * 16);
        }
        const int kr = kk / 3, kc = kk - kr * 3;
        const int pB = (rw + kr) * XTW + kc + l31;
        const ushort* bP0 = Xl + pB * 64;
        const int f0 = pB & 7;                        // (pB+32)&7 == f0
        #pragma unroll
        for (int s = 0; s < 4; ++s) {
            const int ob = (((s * 2 + q) ^ f0) * 8);
            short8x b0 = *(const short8x*)(bP0 + ob);
            short8x b1 = *(const short8x*)(bP0 + 32 * 64 + ob);
            acc[0][0] = __builtin_amdgcn_mfma_f32_32x32x16_bf16(wf[s],     b0, acc[0][0], 0, 0, 0);
            acc[0][1] = __builtin_amdgcn_mfma_f32_32x32x16_bf16(wf[s],     b1, acc[0][1], 0, 0, 0);
            acc[1][0] = __builtin_amdgcn_mfma_f32_32x32x16_bf16(wf[4 + s], b0, acc[1][0], 0, 0, 0);
            acc[1][1] = __builtin_amdgcn_mfma_f32_32x32x16_bf16(wf[4 + s], b1, acc[1][1], 0, 0, 0);
        }
    }

    // ---- terminal epilogue (all stores at once -> L2 merges partial lines) ----
    const int oh = oh0 + rw;
    #pragma unroll
    for (int mt = 0; mt < 2; ++mt)
        #pragma unroll
        for (int nt = 0; nt < 2; ++nt) {
            const int col = nt * 32 + l31;
            if (col < OW) {
                #pragma unroll
                for (int reg = 0; reg < 16; ++reg) {
                    const int co = h * 64 + mt * 32 + 4 * q + (reg & 3) + 8 * (reg >> 2);
                    out[(((size_t)b * CO + co) * OH + oh) * OW + col] = acc[mt][nt][reg] + sB[co];
                }
            }
        }
}

extern "C" void kernel_launch(void* const* d_in, const int* in_sizes, int n_in,
                              void* d_out, int out_size, void* d_ws, size_t ws_size,
                              hipStream_t stream) {
    const float* x    = (const float*)d_in[0];
    const float* wgt  = (const float*)d_in[1];
    const float* bias = (const float*)d_in[2];
    float* out = (float*)d_out;

    wprep<<<dim3(288), 256, 0, stream>>>(wgt);
    xprep<<<dim3(64, 64), 256, 0, stream>>>(x);
    conv_fused<<<dim3(31, 64), 256, 0, stream>>>(bias, out);
}